// Round 6
// baseline (116.443 us; speedup 1.0000x reference)
//
#include <hip/hip_runtime.h>
#include <math.h>

namespace {

constexpr int C_  = 16;
constexpr int OR_ = 8;
constexpr int H_  = 192;
constexpr int W_  = 192;
constexpr int HW_ = H_ * W_;
constexpr int CH_ = OR_ * HW_;
constexpr float PI_F = 3.14159265358979323846f;

// LDS tile: 64x16 output tile, halo 2 each side, ALL 8 orientation planes.
constexpr int TW_ = 68;               // 64 + 2*2
constexpr int TR_ = 20;               // 16 + 2*2
constexpr int PSZ_ = TR_ * TW_;       // 1360 floats per plane
constexpr int TSZ_ = 8 * PSZ_;        // 10880 floats = 43.5 KB

// cos/sin of p*pi/4, exact constants.
constexpr float SQ2H = 0.70710678118654752440f;
__device__ __constant__ float CT8[8] = { 1.0f,  SQ2H,  0.0f, -SQ2H, -1.0f, -SQ2H,  0.0f,  SQ2H };
__device__ __constant__ float ST8[8] = { 0.0f,  SQ2H,  1.0f,  SQ2H,  0.0f, -SQ2H, -1.0f, -SQ2H };

// Zero-padded corner fetch (matches reference _sample's per-corner validity).
__device__ __forceinline__ float corner(const float* __restrict__ p, int iy, int ix) {
    bool valid = ((unsigned)iy < (unsigned)H_) && ((unsigned)ix < (unsigned)W_);
    int yc = min(max(iy, 0), H_ - 1);
    int xc = min(max(ix, 0), W_ - 1);
    float v = p[yc * W_ + xc];
    return valid ? v : 0.0f;
}

// ---------------- fused: out = dilation(convection(u)), all 8 theta per block ----
// 512 threads. One block per (c, xtile, ytile): stage conv for all 8 planes
// once into LDS, then dilate all 8 theta via small runtime-table loops
// (even theta: integer shifts, 1 read/px/offset; odd theta: bilinear).
__global__ __launch_bounds__(512) void fused_kernel(
        const float* __restrict__ u, const float* __restrict__ g0,
        const float* __restrict__ mp, float* __restrict__ out) {
    __shared__ float tile[TSZ_];
    __shared__ float s_k[27];
    __shared__ int   s_relE[4 * 27];
    __shared__ int   s_relO[4 * 27];
    __shared__ float s_wxO[4 * 27];
    __shared__ float s_wyO[4 * 27];

    const int c = blockIdx.z;
    const int t = threadIdx.x;

    // ---- per-block tables (disjoint thread ranges, one barrier below) ----
    if (t < 27) {
        const int hti = t / 9 - 1;
        const int hyi = (t / 3) % 3 - 1;
        const int hxi = t % 3 - 1;
        const float hx = (float)hxi, hy = (float)hyi;
        const float hth  = (float)hti * (2.0f * PI_F / OR_);
        const float half = 0.5f * hth;
        float q;
        if (fabsf(half) < 1e-4f) q = 1.0f - half * half * (1.0f / 3.0f);
        else                     q = half / tanf(half);
        const float c1 = q * hx + half * hy;
        const float c2 = -half * hx + q * hy;
        const float c3 = hth;
        const float m0 = mp[c * 3 + 0], m1 = mp[c * 3 + 1], m2 = mp[c * 3 + 2];
        const float d2 = (m0 * c1) * (m0 * c1) + (m1 * c2) * (m1 * c2) + (m2 * c3) * (m2 * c3);
        const float ee = 2.0f * 0.65f / (2.0f * 0.65f - 1.0f);
        const float nu = (2.0f * 0.65f - 1.0f) * powf(2.0f * 0.65f, -ee);
        s_k[t] = nu * powf(d2, 0.5f * ee);
    } else if (t >= 64 && t < 172) {
        // odd-theta geometry tables
        const int j = t - 64, to = j / 27, o = j % 27;
        const int th = 2 * to + 1;
        const int hti = o / 9 - 1;
        const int hyi = (o / 3) % 3 - 1;
        const int hxi = o % 3 - 1;
        const float ct = CT8[th], st = ST8[th];
        const float sx = ct * (float)hxi - st * (float)hyi;
        const float sy = st * (float)hxi + ct * (float)hyi;
        const float fx = floorf(sx), fy = floorf(sy);
        const int dx = (int)fx, dy = (int)fy;
        const int pl = (th + hti + 8) & 7;
        s_relO[j] = (pl * TR_ + dy) * TW_ + dx;
        s_wxO[j]  = sx - fx;
        s_wyO[j]  = sy - fy;
    } else if (t >= 192 && t < 300) {
        // even-theta: exact integer rotation
        const int j = t - 192, te = j / 27, o = j % 27;
        const int th = 2 * te;
        const int hti = o / 9 - 1;
        const int hyi = (o / 3) % 3 - 1;
        const int hxi = o % 3 - 1;
        const int ctI = (te == 0) ? 1 : (te == 2) ? -1 : 0;
        const int stI = (te == 1) ? 1 : (te == 3) ? -1 : 0;
        const int dx = ctI * hxi - stI * hyi;
        const int dy = stI * hxi + ctI * hyi;
        const int pl = (th + hti + 8) & 7;
        s_relE[j] = (pl * TR_ + dy) * TW_ + dx;
    }

    // ---- conv params + staging (all 512 threads) ----
    const float gx0  = g0[c * 3 + 0];
    const float gy0  = g0[c * 3 + 1];
    const float gth0 = g0[c * 3 + 2];

    float sg, cg;
    sincosf(gth0, &sg, &cg);

    float tc0 = -gth0 * (OR_ / (2.0f * PI_F));
    tc0 = tc0 - floorf(tc0 * (1.0f / OR_)) * (float)OR_;
    const float t0f = floorf(tc0);
    const float wt = tc0 - t0f;
    const int tbase = ((int)t0f) & 7;

    const int bx0 = blockIdx.x * 64 - 2;
    const int by0 = blockIdx.y * 16 - 2;
    const float* __restrict__ cbase = u + c * CH_;

    #pragma unroll
    for (int p = 0; p < 8; ++p) {
        const float ca = CT8[p] * cg + ST8[p] * sg;   // cos(p*pi/4 - gth0)
        const float sa = ST8[p] * cg - CT8[p] * sg;   // sin(p*pi/4 - gth0)
        const float dxs = ca * gx0 - sa * gy0;
        const float dys = sa * gx0 + ca * gy0;
        const float mx = -dxs, my = -dys;
        const float fxi = floorf(mx), fyi = floorf(my);
        const float wxp = mx - fxi, wyp = my - fyi;
        const int sxo = (int)fxi, syo = (int)fyi;
        const int t0i = (tbase + p) & 7;
        const int t1i = (tbase + p + 1) & 7;
        const float* __restrict__ p0 = cbase + t0i * HW_;
        const float* __restrict__ p1 = cbase + t1i * HW_;
        const float w00 = (1.f - wyp) * (1.f - wxp);
        const float w01 = (1.f - wyp) * wxp;
        const float w10 = wyp * (1.f - wxp);
        const float w11 = wyp * wxp;

        for (int i = t; i < PSZ_; i += 512) {
            const int rr  = i / TW_;
            const int col = i - rr * TW_;
            const int gy = by0 + rr;
            const int gx = bx0 + col;
            float v = 0.0f;
            if ((unsigned)gy < (unsigned)H_ && (unsigned)gx < (unsigned)W_) {
                const int ix0 = gx + sxo;
                const int iy0 = gy + syo;
                float v0, v1;
                if (ix0 >= 0 && ix0 + 1 < W_ && iy0 >= 0 && iy0 + 1 < H_) {
                    const int o = iy0 * W_ + ix0;
                    const float a00 = p0[o],      a01 = p0[o + 1];
                    const float a10 = p0[o + W_], a11 = p0[o + W_ + 1];
                    const float b00 = p1[o],      b01 = p1[o + 1];
                    const float b10 = p1[o + W_], b11 = p1[o + W_ + 1];
                    const float ha0 = a00 + wxp * (a01 - a00);
                    const float ha1 = a10 + wxp * (a11 - a10);
                    const float hb0 = b00 + wxp * (b01 - b00);
                    const float hb1 = b10 + wxp * (b11 - b10);
                    v0 = ha0 + wyp * (ha1 - ha0);
                    v1 = hb0 + wyp * (hb1 - hb0);
                } else {
                    v0 = w00 * corner(p0, iy0, ix0)     + w01 * corner(p0, iy0, ix0 + 1)
                       + w10 * corner(p0, iy0 + 1, ix0) + w11 * corner(p0, iy0 + 1, ix0 + 1);
                    v1 = w00 * corner(p1, iy0, ix0)     + w01 * corner(p1, iy0, ix0 + 1)
                       + w10 * corner(p1, iy0 + 1, ix0) + w11 * corner(p1, iy0 + 1, ix0 + 1);
                }
                v = v0 + wt * (v1 - v0);
            }
            tile[p * PSZ_ + i] = v;
        }
    }
    __syncthreads();

    // ---- dilation: 2 px per thread (rows ty, ty+1) ----
    const int tx = t & 63;
    const int ty = (t >> 6) * 2;
    const int lb = (ty + 2) * TW_ + tx + 2;

    float* __restrict__ op = out + c * CH_
                           + (blockIdx.y * 16 + ty) * W_ + blockIdx.x * 64 + tx;

    // even theta: exact integer shifts -> 1 read per px per offset
    #pragma unroll 1
    for (int te = 0; te < 4; ++te) {
        float a0 = -INFINITY, a1 = -INFINITY;
        #pragma unroll 9
        for (int o = 0; o < 27; ++o) {
            const int ad = lb + s_relE[te * 27 + o];
            const float k = s_k[o];
            a0 = fmaxf(a0, tile[ad] - k);
            a1 = fmaxf(a1, tile[ad + TW_] - k);
        }
        float* __restrict__ o2 = op + (2 * te) * HW_;
        o2[0]  = a0;
        o2[W_] = a1;
    }

    // odd theta: bilinear, 3 rows x 2 cols serve both px
    #pragma unroll 1
    for (int to = 0; to < 4; ++to) {
        float a0 = -INFINITY, a1 = -INFINITY;
        #pragma unroll 9
        for (int o = 0; o < 27; ++o) {
            const int j = to * 27 + o;
            const int ad = lb + s_relO[j];
            const float wx = s_wxO[j], wy = s_wyO[j], k = s_k[o];
            const float c00 = tile[ad],           c01 = tile[ad + 1];
            const float c10 = tile[ad + TW_],     c11 = tile[ad + TW_ + 1];
            const float c20 = tile[ad + 2 * TW_], c21 = tile[ad + 2 * TW_ + 1];
            const float h0 = c00 + wx * (c01 - c00);
            const float h1 = c10 + wx * (c11 - c10);
            const float h2 = c20 + wx * (c21 - c20);
            const float v0 = h0 + wy * (h1 - h0);
            const float v1 = h1 + wy * (h2 - h1);
            a0 = fmaxf(a0, v0 - k);
            a1 = fmaxf(a1, v1 - k);
        }
        float* __restrict__ o2 = op + (2 * to + 1) * HW_;
        o2[0]  = a0;
        o2[W_] = a1;
    }
}

} // anonymous namespace

extern "C" void kernel_launch(void* const* d_in, const int* in_sizes, int n_in,
                              void* d_out, int out_size, void* d_ws, size_t ws_size,
                              hipStream_t stream) {
    const float* u   = (const float*)d_in[0];
    const float* g0  = (const float*)d_in[1];
    const float* mpp = (const float*)d_in[2];
    float* out = (float*)d_out;
    float* ws  = (float*)d_ws;

    dim3 grid(W_ / 64, H_ / 16, C_);
    dim3 block(512);

    // iteration 1: ws = dil(conv(u));  iteration 2: out = dil(conv(ws))
    fused_kernel<<<grid, block, 0, stream>>>(u,  g0, mpp, ws);
    fused_kernel<<<grid, block, 0, stream>>>(ws, g0, mpp, out);
}

// Round 7
// 94.014 us; speedup vs baseline: 1.2386x; 1.2386x over previous
//
#include <hip/hip_runtime.h>
#include <math.h>
#include <utility>

namespace {

constexpr int C_  = 16;
constexpr int OR_ = 8;
constexpr int H_  = 192;
constexpr int W_  = 192;
constexpr int HW_ = H_ * W_;
constexpr int CH_ = OR_ * HW_;
constexpr float PI_F = 3.14159265358979323846f;

// LDS tile: 64x16 output tile, halo 2 each side, ALL 8 orientation planes.
// Row = 68 dwords = 272 B (16B multiple) -> aligned float4 windows.
constexpr int TW_ = 68;
constexpr int TR_ = 20;
constexpr int PSZ_ = TR_ * TW_;       // 1360
constexpr int TSZ_ = 8 * PSZ_;        // 10880 floats = 43.5 KB

constexpr float SQ2H = 0.70710678118654752440f;
constexpr float CT8[8] = { 1.0f,  SQ2H,  0.0f, -SQ2H, -1.0f, -SQ2H,  0.0f,  SQ2H };
constexpr float ST8[8] = { 0.0f,  SQ2H,  1.0f,  SQ2H,  0.0f, -SQ2H, -1.0f, -SQ2H };

constexpr int cfloor(float v) {
    return (v >= 0.0f) ? (int)v : (((float)(int)v == v) ? (int)v : (int)v - 1);
}

// Zero-padded corner fetch (matches reference _sample's per-corner validity).
__device__ __forceinline__ float corner(const float* __restrict__ p, int iy, int ix) {
    bool valid = ((unsigned)iy < (unsigned)H_) && ((unsigned)ix < (unsigned)W_);
    int yc = min(max(iy, 0), H_ - 1);
    int xc = min(max(ix, 0), W_ - 1);
    float v = p[yc * W_ + xc];
    return valid ? v : 0.0f;
}

// ---------------- dilation: one offset, fully compile-time geometry ----------------
// Window w[5][8]: rows = output_row-2 .. output_row+2, cols = X-2 .. X+5 (X = 4px base).
// Sample for px j at (row + sy, X+j + sx): corners rows R,R+1 cols Cb+j,Cb+j+1.
template<int P, int HTI, int OO>
__device__ __forceinline__ void off_one(const float (&w)[5][8], const float (&kr)[28],
                                        float (&acc)[8][4]) {
    constexpr int TH  = (P - (HTI - 1) + 8) & 7;   // theta using plane P with hti=HTI-1
    constexpr int hxi = OO % 3 - 1;
    constexpr int hyi = OO / 3 - 1;
    constexpr float ct = CT8[TH];
    constexpr float st = ST8[TH];
    constexpr float sx = ct * (float)hxi - st * (float)hyi;
    constexpr float sy = st * (float)hxi + ct * (float)hyi;
    constexpr int dx = cfloor(sx);
    constexpr int dy = cfloor(sy);
    constexpr float wx = sx - (float)dx;
    constexpr float wy = sy - (float)dy;
    constexpr int R  = dy + 2;    // 0..3
    constexpr int Cb = dx + 2;    // 0..3
    constexpr int O  = HTI * 9 + OO;

    const float k = kr[O];
    #pragma unroll
    for (int j = 0; j < 4; ++j) {
        float v;
        if constexpr (wx == 0.0f && wy == 0.0f) {
            v = w[R][Cb + j];
        } else if constexpr (wy == 0.0f) {
            const float a = w[R][Cb + j];
            v = a + wx * (w[R][Cb + j + 1] - a);
        } else if constexpr (wx == 0.0f) {
            const float a = w[R][Cb + j];
            v = a + wy * (w[R + 1][Cb + j] - a);
        } else {
            const float a0 = w[R][Cb + j];
            const float h0 = a0 + wx * (w[R][Cb + j + 1] - a0);
            const float a1 = w[R + 1][Cb + j];
            const float h1 = a1 + wx * (w[R + 1][Cb + j + 1] - a1);
            v = h0 + wy * (h1 - h0);
        }
        acc[TH][j] = fmaxf(acc[TH][j], v - k);
    }
}

template<int P, int HTI, int... OOs>
__device__ __forceinline__ void off_nine(std::integer_sequence<int, OOs...>,
        const float (&w)[5][8], const float (&kr)[28], float (&acc)[8][4]) {
    (off_one<P, HTI, OOs>(w, kr, acc), ...);
}

// One plane: load 5x8 register window (10 ds_read_b128), feed 3 thetas x 9 offsets.
template<int P>
__device__ __forceinline__ void do_plane(const float* __restrict__ tile, int lb0,
                                         const float (&kr)[28], float (&acc)[8][4]) {
    float w[5][8];
    const float* __restrict__ base = tile + P * PSZ_ + lb0;
    #pragma unroll
    for (int r = 0; r < 5; ++r) {
        *(float4*)&w[r][0] = *(const float4*)&base[r * TW_];
        *(float4*)&w[r][4] = *(const float4*)&base[r * TW_ + 4];
    }
    using Seq9 = std::make_integer_sequence<int, 9>;
    off_nine<P, 0>(Seq9{}, w, kr, acc);
    off_nine<P, 1>(Seq9{}, w, kr, acc);
    off_nine<P, 2>(Seq9{}, w, kr, acc);
}

template<int... Ps>
__device__ __forceinline__ void do_planes(std::integer_sequence<int, Ps...>,
        const float* __restrict__ tile, int lb0, const float (&kr)[28], float (&acc)[8][4]) {
    (do_plane<Ps>(tile, lb0, kr, acc), ...);
}

// ---------------- fused: out = dilation(convection(u)), all 8 theta per block ----
// 256 threads = 16 x-groups (4 adjacent px) x 16 rows. Stage all 8 conv planes
// into LDS once, then register-windowed dilation (planes outer, thetas inner).
__global__ __launch_bounds__(256) void fused_kernel(
        const float* __restrict__ u, const float* __restrict__ g0,
        const float* __restrict__ mp, float* __restrict__ out) {
    __shared__ __align__(16) float tile[TSZ_];
    __shared__ __align__(16) float s_k[28];

    const int c = blockIdx.z;
    const int t = threadIdx.x;

    // ---- kernel-cost table (c-dependent only) ----
    if (t < 28) {
        if (t == 27) {
            s_k[27] = 0.0f;
        } else {
            const int hti = t / 9 - 1;
            const int hyi = (t / 3) % 3 - 1;
            const int hxi = t % 3 - 1;
            const float hx = (float)hxi, hy = (float)hyi;
            const float hth  = (float)hti * (2.0f * PI_F / OR_);
            const float half = 0.5f * hth;
            float q;
            if (fabsf(half) < 1e-4f) q = 1.0f - half * half * (1.0f / 3.0f);
            else                     q = half / tanf(half);
            const float c1 = q * hx + half * hy;
            const float c2 = -half * hx + q * hy;
            const float c3 = hth;
            const float m0 = mp[c * 3 + 0], m1 = mp[c * 3 + 1], m2 = mp[c * 3 + 2];
            const float d2 = (m0 * c1) * (m0 * c1) + (m1 * c2) * (m1 * c2) + (m2 * c3) * (m2 * c3);
            const float ee = 2.0f * 0.65f / (2.0f * 0.65f - 1.0f);
            const float nu = (2.0f * 0.65f - 1.0f) * powf(2.0f * 0.65f, -ee);
            s_k[t] = nu * powf(d2, 0.5f * ee);
        }
    }

    // ---- conv params + staging (all 256 threads) ----
    const float gx0  = g0[c * 3 + 0];
    const float gy0  = g0[c * 3 + 1];
    const float gth0 = g0[c * 3 + 2];

    float sg, cg;
    sincosf(gth0, &sg, &cg);

    float tc0 = -gth0 * (OR_ / (2.0f * PI_F));
    tc0 = tc0 - floorf(tc0 * (1.0f / OR_)) * (float)OR_;
    const float t0f = floorf(tc0);
    const float wt = tc0 - t0f;
    const int tbase = ((int)t0f) & 7;

    const int bx0 = blockIdx.x * 64 - 2;
    const int by0 = blockIdx.y * 16 - 2;
    const float* __restrict__ cbase = u + c * CH_;

    #pragma unroll
    for (int p = 0; p < 8; ++p) {
        const float ca = CT8[p] * cg + ST8[p] * sg;   // cos(p*pi/4 - gth0)
        const float sa = ST8[p] * cg - CT8[p] * sg;   // sin(p*pi/4 - gth0)
        const float dxs = ca * gx0 - sa * gy0;
        const float dys = sa * gx0 + ca * gy0;
        const float mx = -dxs, my = -dys;
        const float fxi = floorf(mx), fyi = floorf(my);
        const float wxp = mx - fxi, wyp = my - fyi;
        const int sxo = (int)fxi, syo = (int)fyi;
        const int t0i = (tbase + p) & 7;
        const int t1i = (tbase + p + 1) & 7;
        const float* __restrict__ p0 = cbase + t0i * HW_;
        const float* __restrict__ p1 = cbase + t1i * HW_;
        const float w00 = (1.f - wyp) * (1.f - wxp);
        const float w01 = (1.f - wyp) * wxp;
        const float w10 = wyp * (1.f - wxp);
        const float w11 = wyp * wxp;

        for (int i = t; i < PSZ_; i += 256) {
            const int rr  = i / TW_;
            const int col = i - rr * TW_;
            const int gy = by0 + rr;
            const int gx = bx0 + col;
            float v = 0.0f;
            if ((unsigned)gy < (unsigned)H_ && (unsigned)gx < (unsigned)W_) {
                const int ix0 = gx + sxo;
                const int iy0 = gy + syo;
                float v0, v1;
                if (ix0 >= 0 && ix0 + 1 < W_ && iy0 >= 0 && iy0 + 1 < H_) {
                    const int o = iy0 * W_ + ix0;
                    const float a00 = p0[o],      a01 = p0[o + 1];
                    const float a10 = p0[o + W_], a11 = p0[o + W_ + 1];
                    const float b00 = p1[o],      b01 = p1[o + 1];
                    const float b10 = p1[o + W_], b11 = p1[o + W_ + 1];
                    const float ha0 = a00 + wxp * (a01 - a00);
                    const float ha1 = a10 + wxp * (a11 - a10);
                    const float hb0 = b00 + wxp * (b01 - b00);
                    const float hb1 = b10 + wxp * (b11 - b10);
                    v0 = ha0 + wyp * (ha1 - ha0);
                    v1 = hb0 + wyp * (hb1 - hb0);
                } else {
                    v0 = w00 * corner(p0, iy0, ix0)     + w01 * corner(p0, iy0, ix0 + 1)
                       + w10 * corner(p0, iy0 + 1, ix0) + w11 * corner(p0, iy0 + 1, ix0 + 1);
                    v1 = w00 * corner(p1, iy0, ix0)     + w01 * corner(p1, iy0, ix0 + 1)
                       + w10 * corner(p1, iy0 + 1, ix0) + w11 * corner(p1, iy0 + 1, ix0 + 1);
                }
                v = v0 + wt * (v1 - v0);
            }
            tile[p * PSZ_ + i] = v;
        }
    }
    __syncthreads();

    // ---- hoist k-table into registers (7 x float4, broadcast reads) ----
    float kr[28];
    #pragma unroll
    for (int q = 0; q < 7; ++q)
        *(float4*)&kr[4 * q] = *(const float4*)&s_k[4 * q];

    // ---- dilation: 4 adjacent x px per thread, one row, all 8 thetas ----
    const int xg = t & 15;          // x-group: px X..X+3, X = xg*4
    const int y  = t >> 4;          // output row 0..15
    // window base: tile rows y..y+4 (= global y-2..y+2), cols xg*4..xg*4+7 (= X-2..X+5)
    const int lb0 = y * TW_ + xg * 4;

    float acc[8][4];
    #pragma unroll
    for (int th = 0; th < 8; ++th)
        #pragma unroll
        for (int j = 0; j < 4; ++j)
            acc[th][j] = -INFINITY;

    do_planes(std::make_integer_sequence<int, 8>{}, tile, lb0, kr, acc);

    // ---- store: float4 per theta ----
    const int gx = blockIdx.x * 64 + xg * 4;
    const int gy = blockIdx.y * 16 + y;
    float* __restrict__ op = out + c * CH_ + gy * W_ + gx;
    #pragma unroll
    for (int th = 0; th < 8; ++th) {
        float4 r;
        r.x = acc[th][0]; r.y = acc[th][1]; r.z = acc[th][2]; r.w = acc[th][3];
        *(float4*)&op[th * HW_] = r;
    }
}

} // anonymous namespace

extern "C" void kernel_launch(void* const* d_in, const int* in_sizes, int n_in,
                              void* d_out, int out_size, void* d_ws, size_t ws_size,
                              hipStream_t stream) {
    const float* u   = (const float*)d_in[0];
    const float* g0  = (const float*)d_in[1];
    const float* mpp = (const float*)d_in[2];
    float* out = (float*)d_out;
    float* ws  = (float*)d_ws;

    dim3 grid(W_ / 64, H_ / 16, C_);
    dim3 block(256);

    // iteration 1: ws = dil(conv(u));  iteration 2: out = dil(conv(ws))
    fused_kernel<<<grid, block, 0, stream>>>(u,  g0, mpp, ws);
    fused_kernel<<<grid, block, 0, stream>>>(ws, g0, mpp, out);
}

// Round 8
// 86.546 us; speedup vs baseline: 1.3454x; 1.0863x over previous
//
#include <hip/hip_runtime.h>
#include <math.h>
#include <utility>

namespace {

constexpr int C_  = 16;
constexpr int OR_ = 8;
constexpr int H_  = 192;
constexpr int W_  = 192;
constexpr int HW_ = H_ * W_;
constexpr int CH_ = OR_ * HW_;
constexpr float PI_F = 3.14159265358979323846f;

// LDS tile for dil: 64x16 output tile, halo 2 each side, 3 orientation planes.
// Row = 68 dwords = 272 B (16B multiple) -> aligned float4 windows.
constexpr int TW_ = 68;
constexpr int TR_ = 20;
constexpr int PSZ_ = TR_ * TW_;        // 1360 floats per plane
constexpr int TSZ3_ = 3 * PSZ_;        // 4080 floats = 16.3 KB

constexpr float SQ2H = 0.70710678118654752440f;
constexpr float CT8[8] = { 1.0f,  SQ2H,  0.0f, -SQ2H, -1.0f, -SQ2H,  0.0f,  SQ2H };
constexpr float ST8[8] = { 0.0f,  SQ2H,  1.0f,  SQ2H,  0.0f, -SQ2H, -1.0f, -SQ2H };

constexpr int cfloor(float v) {
    return (v >= 0.0f) ? (int)v : (((float)(int)v == v) ? (int)v : (int)v - 1);
}

// Zero-padded corner fetch (matches reference _sample's per-corner validity).
__device__ __forceinline__ float corner(const float* __restrict__ p, int iy, int ix) {
    bool valid = ((unsigned)iy < (unsigned)H_) && ((unsigned)ix < (unsigned)W_);
    int yc = min(max(iy, 0), H_ - 1);
    int xc = min(max(ix, 0), W_ - 1);
    float v = p[yc * W_ + xc];
    return valid ? v : 0.0f;
}

// ---------------- convection_m2 (proven round-2/3 kernel) ----------------
__global__ __launch_bounds__(256) void conv_kernel(
        const float* __restrict__ u, const float* __restrict__ g0,
        float* __restrict__ out) {
    const int tx  = threadIdx.x & 63;
    const int ty0 = (threadIdx.x >> 6) * 4;
    const int x   = blockIdx.x * 64 + tx;
    const int y0  = blockIdx.y * 16 + ty0;
    const int z = blockIdx.z;
    const int c  = z >> 3;
    const int th = z & 7;

    const float gx0  = g0[c * 3 + 0];
    const float gy0  = g0[c * 3 + 1];
    const float gth0 = g0[c * 3 + 2];

    const float a = (float)th * (2.0f * PI_F / OR_) - gth0;
    float sa, ca;
    sincosf(a, &sa, &ca);
    const float dxs = ca * gx0 - sa * gy0;
    const float dys = sa * gx0 + ca * gy0;

    const float fx = (float)x - dxs;
    const float fy = (float)y0 - dys;
    const float fx0 = floorf(fx), fy0 = floorf(fy);
    const float wx = fx - fx0, wy = fy - fy0;
    const int ix0 = (int)fx0, iy0 = (int)fy0;

    float tc = (float)th - gth0 * (OR_ / (2.0f * PI_F));
    tc = tc - floorf(tc * (1.0f / OR_)) * (float)OR_;
    const float t0f = floorf(tc);
    const float wt = tc - t0f;
    const int t0i = ((int)t0f) & 7;
    const int t1i = (t0i + 1) & 7;

    const float* __restrict__ p0 = u + c * CH_ + t0i * HW_;
    const float* __restrict__ p1 = u + c * CH_ + t1i * HW_;

    float r0, r1, r2, r3;
    if (ix0 >= 0 && ix0 + 1 < W_ && iy0 >= 0 && iy0 + 4 < H_) {
        const int o = iy0 * W_ + ix0;
        float a00 = p0[o],          a01 = p0[o + 1];
        float a10 = p0[o + W_],     a11 = p0[o + W_ + 1];
        float a20 = p0[o + 2 * W_], a21 = p0[o + 2 * W_ + 1];
        float a30 = p0[o + 3 * W_], a31 = p0[o + 3 * W_ + 1];
        float a40 = p0[o + 4 * W_], a41 = p0[o + 4 * W_ + 1];
        float b00 = p1[o],          b01 = p1[o + 1];
        float b10 = p1[o + W_],     b11 = p1[o + W_ + 1];
        float b20 = p1[o + 2 * W_], b21 = p1[o + 2 * W_ + 1];
        float b30 = p1[o + 3 * W_], b31 = p1[o + 3 * W_ + 1];
        float b40 = p1[o + 4 * W_], b41 = p1[o + 4 * W_ + 1];
        float ha0 = a00 + wx * (a01 - a00);
        float ha1 = a10 + wx * (a11 - a10);
        float ha2 = a20 + wx * (a21 - a20);
        float ha3 = a30 + wx * (a31 - a30);
        float ha4 = a40 + wx * (a41 - a40);
        float hb0 = b00 + wx * (b01 - b00);
        float hb1 = b10 + wx * (b11 - b10);
        float hb2 = b20 + wx * (b21 - b20);
        float hb3 = b30 + wx * (b31 - b30);
        float hb4 = b40 + wx * (b41 - b40);
        float va0 = ha0 + wy * (ha1 - ha0);
        float va1 = ha1 + wy * (ha2 - ha1);
        float va2 = ha2 + wy * (ha3 - ha2);
        float va3 = ha3 + wy * (ha4 - ha3);
        float vb0 = hb0 + wy * (hb1 - hb0);
        float vb1 = hb1 + wy * (hb2 - hb1);
        float vb2 = hb2 + wy * (hb3 - hb2);
        float vb3 = hb3 + wy * (hb4 - hb3);
        r0 = va0 + wt * (vb0 - va0);
        r1 = va1 + wt * (vb1 - va1);
        r2 = va2 + wt * (vb2 - va2);
        r3 = va3 + wt * (vb3 - va3);
    } else {
        const float w00 = (1.f - wy) * (1.f - wx);
        const float w01 = (1.f - wy) * wx;
        const float w10 = wy * (1.f - wx);
        const float w11 = wy * wx;
        float rr[4];
        #pragma unroll
        for (int j = 0; j < 4; ++j) {
            const int iy = iy0 + j;
            float v0 = w00 * corner(p0, iy, ix0)     + w01 * corner(p0, iy, ix0 + 1)
                     + w10 * corner(p0, iy + 1, ix0) + w11 * corner(p0, iy + 1, ix0 + 1);
            float v1 = w00 * corner(p1, iy, ix0)     + w01 * corner(p1, iy, ix0 + 1)
                     + w10 * corner(p1, iy + 1, ix0) + w11 * corner(p1, iy + 1, ix0 + 1);
            rr[j] = v0 + wt * (v1 - v0);
        }
        r0 = rr[0]; r1 = rr[1]; r2 = rr[2]; r3 = rr[3];
    }
    float* __restrict__ op = out + c * CH_ + th * HW_ + y0 * W_ + x;
    op[0]      = r0;
    op[W_]     = r1;
    op[2 * W_] = r2;
    op[3 * W_] = r3;
}

// ---------------- dilation: register-window, theta compile-time ----------------
// Window w[5][8]: tile rows y..y+4 (global y-2..y+2), cols xg*4..xg*4+7 (global X-2..X+5).
template<int TH, int PP, int OO>
__device__ __forceinline__ void off_one(const float (&w)[5][8],
                                        const float* __restrict__ sk, float (&acc)[4]) {
    constexpr int hxi = OO % 3 - 1;
    constexpr int hyi = OO / 3 - 1;
    constexpr float ct = CT8[TH];
    constexpr float st = ST8[TH];
    constexpr float sx = ct * (float)hxi - st * (float)hyi;
    constexpr float sy = st * (float)hxi + ct * (float)hyi;
    constexpr int dx = cfloor(sx);
    constexpr int dy = cfloor(sy);
    constexpr float wx = sx - (float)dx;
    constexpr float wy = sy - (float)dy;
    constexpr int R  = dy + 2;    // 0..3
    constexpr int Cb = dx + 2;    // 0..3

    const float k = sk[PP * 9 + OO];   // LDS broadcast (wave-uniform)
    #pragma unroll
    for (int j = 0; j < 4; ++j) {
        float v;
        if constexpr (wx == 0.0f && wy == 0.0f) {
            v = w[R][Cb + j];
        } else if constexpr (wy == 0.0f) {
            const float a = w[R][Cb + j];
            v = a + wx * (w[R][Cb + j + 1] - a);
        } else if constexpr (wx == 0.0f) {
            const float a = w[R][Cb + j];
            v = a + wy * (w[R + 1][Cb + j] - a);
        } else {
            const float a0 = w[R][Cb + j];
            const float h0 = a0 + wx * (w[R][Cb + j + 1] - a0);
            const float a1 = w[R + 1][Cb + j];
            const float h1 = a1 + wx * (w[R + 1][Cb + j + 1] - a1);
            v = h0 + wy * (h1 - h0);
        }
        acc[j] = fmaxf(acc[j], v - k);
    }
}

template<int TH, int PP, int... OOs>
__device__ __forceinline__ void off_nine(std::integer_sequence<int, OOs...>,
        const float (&w)[5][8], const float* __restrict__ sk, float (&acc)[4]) {
    (off_one<TH, PP, OOs>(w, sk, acc), ...);
}

// One staged plane PP (hti = PP-1): 10 ds_read_b128 window, 9 offsets.
template<int TH, int PP>
__device__ __forceinline__ void do_plane(const float* __restrict__ tile, int lb0,
                                         const float* __restrict__ sk, float (&acc)[4]) {
    float w[5][8];
    const float* __restrict__ base = tile + PP * PSZ_ + lb0;
    #pragma unroll
    for (int r = 0; r < 5; ++r) {
        *(float4*)&w[r][0] = *(const float4*)&base[r * TW_];
        *(float4*)&w[r][4] = *(const float4*)&base[r * TW_ + 4];
    }
    off_nine<TH, PP>(std::make_integer_sequence<int, 9>{}, w, sk, acc);
}

template<int TH>
__device__ __forceinline__ void dil_theta(const float* __restrict__ tile, int lb0,
        const float* __restrict__ sk, float (&acc)[4]) {
    do_plane<TH, 0>(tile, lb0, sk, acc);
    do_plane<TH, 1>(tile, lb0, sk, acc);
    do_plane<TH, 2>(tile, lb0, sk, acc);
}

// One block per (c,theta): stage 3 conv-output planes (plain float2 copy from
// global, zero-padded), then register-window dilation. 4608 blocks.
__global__ __launch_bounds__(256) void dil_kernel(
        const float* __restrict__ u, const float* __restrict__ mp,
        float* __restrict__ out) {
    __shared__ __align__(16) float tile[TSZ3_];
    __shared__ float s_k[27];

    const int z = blockIdx.z;
    const int c  = z >> 3;
    const int th = z & 7;
    const int t = threadIdx.x;

    if (t < 27) {
        const int hti = t / 9 - 1;
        const int hyi = (t / 3) % 3 - 1;
        const int hxi = t % 3 - 1;
        const float hx = (float)hxi, hy = (float)hyi;
        const float hth  = (float)hti * (2.0f * PI_F / OR_);
        const float half = 0.5f * hth;
        float q;
        if (fabsf(half) < 1e-4f) q = 1.0f - half * half * (1.0f / 3.0f);
        else                     q = half / tanf(half);
        const float c1 = q * hx + half * hy;
        const float c2 = -half * hx + q * hy;
        const float c3 = hth;
        const float m0 = mp[c * 3 + 0], m1 = mp[c * 3 + 1], m2 = mp[c * 3 + 2];
        const float d2 = (m0 * c1) * (m0 * c1) + (m1 * c2) * (m1 * c2) + (m2 * c3) * (m2 * c3);
        const float ee = 2.0f * 0.65f / (2.0f * 0.65f - 1.0f);
        const float nu = (2.0f * 0.65f - 1.0f) * powf(2.0f * 0.65f, -ee);
        s_k[t] = nu * powf(d2, 0.5f * ee);
    }

    // ---- stage 3 planes as float2 copies (bx0 even -> never straddles pad) ----
    const int bx0 = blockIdx.x * 64 - 2;
    const int by0 = blockIdx.y * 16 - 2;
    const float* __restrict__ cbase = u + c * CH_;
    float2* __restrict__ t2 = (float2*)tile;
    constexpr int TW2 = TW_ / 2;            // 34 float2 per row
    #pragma unroll
    for (int k = 0; k < 8; ++k) {
        const int i = t + k * 256;
        if (i < TSZ3_ / 2) {
            const int r    = i / TW2;
            const int col2 = i - r * TW2;
            const int pp   = r / TR_;
            const int rr   = r - pp * TR_;
            const int gy = by0 + rr;
            const int gx = bx0 + col2 * 2;
            const int plane = (th + pp - 1 + OR_) & 7;
            float2 v = make_float2(0.0f, 0.0f);
            if ((unsigned)gy < (unsigned)H_ && (unsigned)gx < (unsigned)W_)
                v = *(const float2*)&cbase[plane * HW_ + gy * W_ + gx];
            t2[i] = v;
        }
    }
    __syncthreads();

    // ---- dilation: 4 adjacent x px per thread, one row ----
    const int xg = t & 15;
    const int y  = t >> 4;
    const int lb0 = y * TW_ + xg * 4;

    float acc[4];
    #pragma unroll
    for (int j = 0; j < 4; ++j) acc[j] = -INFINITY;

    switch (th) {
        case 0: dil_theta<0>(tile, lb0, s_k, acc); break;
        case 1: dil_theta<1>(tile, lb0, s_k, acc); break;
        case 2: dil_theta<2>(tile, lb0, s_k, acc); break;
        case 3: dil_theta<3>(tile, lb0, s_k, acc); break;
        case 4: dil_theta<4>(tile, lb0, s_k, acc); break;
        case 5: dil_theta<5>(tile, lb0, s_k, acc); break;
        case 6: dil_theta<6>(tile, lb0, s_k, acc); break;
        case 7: dil_theta<7>(tile, lb0, s_k, acc); break;
        default: __builtin_unreachable();
    }

    const int gx = blockIdx.x * 64 + xg * 4;
    const int gy = blockIdx.y * 16 + y;
    float4 r;
    r.x = acc[0]; r.y = acc[1]; r.z = acc[2]; r.w = acc[3];
    *(float4*)&out[c * CH_ + th * HW_ + gy * W_ + gx] = r;
}

} // anonymous namespace

extern "C" void kernel_launch(void* const* d_in, const int* in_sizes, int n_in,
                              void* d_out, int out_size, void* d_ws, size_t ws_size,
                              hipStream_t stream) {
    const float* u   = (const float*)d_in[0];
    const float* g0  = (const float*)d_in[1];
    const float* mpp = (const float*)d_in[2];
    float* out = (float*)d_out;
    float* ws  = (float*)d_ws;

    dim3 grid(W_ / 64, H_ / 16, C_ * OR_);
    dim3 block(256);

    // iter 1
    conv_kernel<<<grid, block, 0, stream>>>(u,   g0,  ws);
    dil_kernel <<<grid, block, 0, stream>>>(ws,  mpp, out);
    // iter 2
    conv_kernel<<<grid, block, 0, stream>>>(out, g0,  ws);
    dil_kernel <<<grid, block, 0, stream>>>(ws,  mpp, out);
}